// Round 1
// baseline (74.816 us; speedup 1.0000x reference)
//
#include <hip/hip_runtime.h>

#define EPS 1e-5f

// Workspace layout:
//   [0]      double acc[8]   : s1,s2,s3,s4,s5,nbg,nfg,nng   (64 bytes)
//   [64]     int offs[n_dst*Lmax]  : path offsets (dy*W+dx)
//   [after]  int doffs[n_dst]      : dst offsets

__global__ void setup_kernel(const int* __restrict__ path_idx,
                             const int* __restrict__ src_idx,
                             const int* __restrict__ dst_idx,
                             int n_dst, int Lmax, int n_pos,
                             double* __restrict__ acc,
                             int* __restrict__ offs,
                             int* __restrict__ doffs) {
    int tid = threadIdx.x;
    if (tid < 8) acc[tid] = 0.0;
    int base0 = src_idx[0];   // = rf
    int total = n_dst * Lmax;
    for (int i = tid; i < total; i += blockDim.x)
        offs[i] = path_idx[(long long)i * n_pos] - base0;
    for (int i = tid; i < n_dst; i += blockDim.x)
        doffs[i] = dst_idx[(long long)i * n_pos] - base0;
}

__launch_bounds__(256)
__global__ void loss_kernel(const float* __restrict__ edge,
                            const float* __restrict__ dp,
                            const float* __restrict__ bg,
                            const float* __restrict__ fg,
                            const float* __restrict__ ng,
                            const float* __restrict__ dt,
                            const int*  __restrict__ src_idx,
                            const int*  __restrict__ offs,
                            const int*  __restrict__ doffs,
                            int n_dst, int Lmax, int n_pos, int B, int HW,
                            int bpd, double* __restrict__ acc) {
    __shared__ int s_offs[64];
    int d  = blockIdx.x / bpd;
    int pb = blockIdx.x - d * bpd;
    int tid = threadIdx.x;
    if (tid < Lmax) s_offs[tid] = offs[d * Lmax + tid];
    __syncthreads();

    int p = pb * 256 + tid;
    float s1 = 0.f, s2 = 0.f, s3 = 0.f, s4 = 0.f, s5 = 0.f;
    float snbg = 0.f, snfg = 0.f, snng = 0.f;

    if (p < n_pos) {
        int base = src_idx[p];
        int doff = doffs[d];
        float dt0 = dt[d];
        float dt1 = dt[n_dst + d];
        long long strideB = (long long)n_dst * n_pos;
        long long lab0 = (long long)d * n_pos + p;

        for (int b = 0; b < B; ++b) {
            const float* eb = edge + (long long)b * HW;
            float m = -1e30f;
            for (int l = 0; l < Lmax; ++l)
                m = fmaxf(m, eb[base + s_offs[l]]);
            // max of sigmoid == sigmoid of max (monotone)
            float sig  = 1.0f / (1.0f + expf(-m));
            float posl = -logf(1.0f - sig + EPS);
            float negl = -logf(sig + EPS);

            long long li = lab0 + (long long)b * strideB;
            float vb = bg[li];
            float vf = fg[li];
            float vn = ng[li];
            snbg += vb; snfg += vf; snng += vn;
            s1 += vb * posl;
            s2 += vf * posl;
            s3 += vn * negl;

            const float* dpb = dp + (long long)b * 2 * HW;
            float pd0 = dpb[base]      - dpb[base + doff];
            float pd1 = dpb[HW + base] - dpb[HW + base + doff];
            s4 += vf * (fabsf(pd0 - dt0) + fabsf(pd1 - dt1));
            s5 += vb * (fabsf(pd0) + fabsf(pd1));
        }
    }

    // block reduction: wave64 shfl, then LDS across 4 waves, then f64 atomics
    float vals[8] = {s1, s2, s3, s4, s5, snbg, snfg, snng};
    __shared__ float red[4][8];
    int lane = tid & 63, wave = tid >> 6;
#pragma unroll
    for (int i = 0; i < 8; ++i) {
        float v = vals[i];
        for (int o = 32; o > 0; o >>= 1) v += __shfl_down(v, o);
        if (lane == 0) red[wave][i] = v;
    }
    __syncthreads();
    if (tid < 8) {
        float t = red[0][tid] + red[1][tid] + red[2][tid] + red[3][tid];
        atomicAdd(&acc[tid], (double)t);
    }
}

__global__ void finalize_kernel(const double* __restrict__ acc,
                                float* __restrict__ out) {
    double eps = 1e-5;
    double bg_pos = acc[0] / (acc[5] + eps);
    double fg_pos = acc[1] / (acc[6] + eps);
    double pos = 0.5 * bg_pos + 0.5 * fg_pos;
    double neg = acc[2] / (acc[7] + eps);
    double dfg = acc[3] / (2.0 * acc[6] + eps);
    double dbg = acc[4] / (2.0 * acc[5] + eps);
    out[0] = (float)(0.5 * (pos + neg) + 0.5 * (dfg + dbg));
}

extern "C" void kernel_launch(void* const* d_in, const int* in_sizes, int n_in,
                              void* d_out, int out_size, void* d_ws, size_t ws_size,
                              hipStream_t stream) {
    const float* edge = (const float*)d_in[0];
    const float* dp   = (const float*)d_in[1];
    const float* bg   = (const float*)d_in[2];
    const float* fg   = (const float*)d_in[3];
    const float* ng   = (const float*)d_in[4];
    const float* dt   = (const float*)d_in[5];
    const int* path_idx = (const int*)d_in[6];
    const int* src_idx  = (const int*)d_in[7];
    const int* dst_idx  = (const int*)d_in[8];

    int n_pos = in_sizes[7];
    int n_dst = in_sizes[8] / n_pos;
    int Lmax  = in_sizes[6] / (n_dst * n_pos);
    int B     = in_sizes[2] / (n_dst * n_pos);
    int HW    = in_sizes[0] / B;

    double* acc = (double*)d_ws;
    int* offs   = (int*)((char*)d_ws + 64);
    int* doffs  = offs + n_dst * Lmax;

    setup_kernel<<<1, 256, 0, stream>>>(path_idx, src_idx, dst_idx,
                                        n_dst, Lmax, n_pos, acc, offs, doffs);

    int bpd = (n_pos + 255) / 256;
    loss_kernel<<<dim3(n_dst * bpd), 256, 0, stream>>>(
        edge, dp, bg, fg, ng, dt, src_idx, offs, doffs,
        n_dst, Lmax, n_pos, B, HW, bpd, acc);

    finalize_kernel<<<1, 1, 0, stream>>>(acc, (float*)d_out);
}

// Round 3
// 51.270 us; speedup vs baseline: 1.4593x; 1.4593x over previous
//
#include <hip/hip_runtime.h>

#define EPS 1e-5f

typedef float float4a __attribute__((ext_vector_type(4), aligned(4)));
typedef float float4v __attribute__((ext_vector_type(4)));

// ---------------- setup: extract constant offsets --------------------------
__global__ void setup_kernel(const int* __restrict__ path_idx,
                             const int* __restrict__ src_idx,
                             const int* __restrict__ dst_idx,
                             int n_dst, int Lmax, long long n_pos,
                             int* __restrict__ offs,
                             int* __restrict__ doffs,
                             double* __restrict__ acc) {
    int tid = threadIdx.x;
    if (tid < 8) acc[tid] = 0.0;
    int base0 = src_idx[0];
    int total = n_dst * Lmax;
    for (int i = tid; i < total; i += blockDim.x)
        offs[i] = path_idx[(long long)i * n_pos] - base0;
    for (int i = tid; i < n_dst; i += blockDim.x)
        doffs[i] = dst_idx[(long long)i * n_pos] - base0;
}

// ---------------- main fused kernel ----------------------------------------
// Each thread: 4 consecutive p, B_PER batches. LMAX >= runtime Lrt (padded
// with off[0]; duplicate loads are harmless for max).
template<int LMAX, int B_PER, bool USE_ATOMIC>
__launch_bounds__(256)
__global__ void loss_kernel(const float* __restrict__ edge,
                            const float* __restrict__ dp,
                            const float* __restrict__ bgl,
                            const float* __restrict__ fgl,
                            const float* __restrict__ ngl,
                            const float* __restrict__ dt,
                            const int*  __restrict__ src_idx,
                            const int*  __restrict__ offs,
                            const int*  __restrict__ doffs,
                            int n_dst, int n_pos, int HW, int B,
                            int PB, int BG, int Lrt,
                            float* __restrict__ partials, int nblk,
                            double* __restrict__ acc) {
    int bid = blockIdx.x;
    int d   = bid / (PB * BG);
    int rem = bid - d * (PB * BG);
    int pb  = rem / BG;
    int bg  = rem - pb * BG;
    int tid = threadIdx.x;

    int off[LMAX];
#pragma unroll
    for (int l = 0; l < LMAX; ++l) {
        int li = (l < Lrt) ? l : (Lrt - 1);
        off[l] = offs[d * Lrt + li];
    }
    int   doff = doffs[d];
    float dt0  = dt[d];
    float dt1  = dt[n_dst + d];

    float s1 = 0.f, s2 = 0.f, s3 = 0.f, s4 = 0.f, s5 = 0.f;
    float snb = 0.f, snf = 0.f, snn = 0.f;

    int p0 = (pb * 256 + tid) * 4;
    if (p0 < n_pos) {
        int base = src_idx[p0];
        long long strideB = (long long)n_dst * n_pos;
        int b0 = bg * B_PER;

        const float* ebase  = edge + (long long)b0 * HW + base;
        const float* dpbase = dp + (long long)b0 * 2 * HW + base;
        const float* bgp = bgl + (long long)b0 * strideB + (long long)d * n_pos + p0;
        const float* fgp = fgl + (long long)b0 * strideB + (long long)d * n_pos + p0;
        const float* ngp = ngl + (long long)b0 * strideB + (long long)d * n_pos + p0;

#pragma unroll
        for (int bb = 0; bb < B_PER; ++bb) {
            if (b0 + bb >= B) break;

            // ---- max over path (sigmoid monotone: take max of logits) ----
            float m0 = -1e30f, m1 = -1e30f, m2 = -1e30f, m3 = -1e30f;
#pragma unroll
            for (int l = 0; l < LMAX; ++l) {
                float4a v = *(const float4a*)(ebase + off[l]);
                m0 = fmaxf(m0, v[0]); m1 = fmaxf(m1, v[1]);
                m2 = fmaxf(m2, v[2]); m3 = fmaxf(m3, v[3]);
            }
            m0 = fmaxf(m0, -80.f); m1 = fmaxf(m1, -80.f);
            m2 = fmaxf(m2, -80.f); m3 = fmaxf(m3, -80.f);

            // sig = 1/(1+t), t = e^-m, u = 1+t.
            // posl = -log(1-sig+eps) = ln(u) - ln(t + eps*u)
            // negl = -log(sig+eps)   = ln(u) - ln(1 + eps*u)
            float pl[4], nl[4];
            float mm[4] = {m0, m1, m2, m3};
#pragma unroll
            for (int k = 0; k < 4; ++k) {
                float t  = __expf(-mm[k]);
                float u  = 1.0f + t;
                float lu = __logf(u);
                pl[k] = lu - __logf(fmaf(EPS, u, t));
                nl[k] = lu - __logf(fmaf(EPS, u, 1.0f));
            }

            // ---- labels (the HBM stream) ----
            float4v vb = *(const float4v*)bgp;
            float4v vf = *(const float4v*)fgp;
            float4v vn = *(const float4v*)ngp;
            snb += (vb[0] + vb[1]) + (vb[2] + vb[3]);
            snf += (vf[0] + vf[1]) + (vf[2] + vf[3]);
            snn += (vn[0] + vn[1]) + (vn[2] + vn[3]);
#pragma unroll
            for (int k = 0; k < 4; ++k) {
                s1 = fmaf(vb[k], pl[k], s1);
                s2 = fmaf(vf[k], pl[k], s2);
                s3 = fmaf(vn[k], nl[k], s3);
            }

            // ---- displacement part ----
            float4v a0 = *(const float4v*)(dpbase);
            float4a c0 = *(const float4a*)(dpbase + doff);
            float4v a1 = *(const float4v*)(dpbase + HW);
            float4a c1 = *(const float4a*)(dpbase + HW + doff);
#pragma unroll
            for (int k = 0; k < 4; ++k) {
                float q0 = a0[k] - c0[k];
                float q1 = a1[k] - c1[k];
                s4 = fmaf(vf[k], fabsf(q0 - dt0) + fabsf(q1 - dt1), s4);
                s5 = fmaf(vb[k], fabsf(q0) + fabsf(q1), s5);
            }

            ebase  += HW;
            dpbase += 2 * HW;
            bgp += strideB; fgp += strideB; ngp += strideB;
        }
    }

    // ---- block reduction: wave shfl -> LDS -> one write per accumulator ----
    float vals[8] = {s1, s2, s3, s4, s5, snb, snf, snn};
    __shared__ float red[4][8];
    int lane = tid & 63, wv = tid >> 6;
#pragma unroll
    for (int i = 0; i < 8; ++i) {
        float v = vals[i];
        for (int o = 32; o > 0; o >>= 1) v += __shfl_down(v, o);
        if (lane == 0) red[wv][i] = v;
    }
    __syncthreads();
    if (tid < 8) {
        float t = red[0][tid] + red[1][tid] + red[2][tid] + red[3][tid];
        if (USE_ATOMIC) atomicAdd(&acc[tid], (double)t);
        else            partials[(long long)tid * nblk + bid] = t;
    }
}

// ---------------- reduction of per-block partials --------------------------
__global__ void reduce_kernel(const float* __restrict__ partials, int nblk,
                              float* __restrict__ out) {
    int w = threadIdx.x >> 6, lane = threadIdx.x & 63;
    double s = 0.0;
    const float* src = partials + (long long)w * nblk;
    for (int i = lane; i < nblk; i += 64) s += (double)src[i];
    for (int o = 32; o > 0; o >>= 1) s += __shfl_down(s, o);
    __shared__ double sums[8];
    if (lane == 0) sums[w] = s;
    __syncthreads();
    if (threadIdx.x == 0) {
        double eps = 1e-5;
        double bg_pos = sums[0] / (sums[5] + eps);
        double fg_pos = sums[1] / (sums[6] + eps);
        double pos = 0.5 * bg_pos + 0.5 * fg_pos;
        double neg = sums[2] / (sums[7] + eps);
        double dfg = sums[3] / (2.0 * sums[6] + eps);
        double dbg = sums[4] / (2.0 * sums[5] + eps);
        out[0] = (float)(0.5 * (pos + neg) + 0.5 * (dfg + dbg));
    }
}

__global__ void finalize_atomic_kernel(const double* __restrict__ acc,
                                       float* __restrict__ out) {
    double eps = 1e-5;
    double bg_pos = acc[0] / (acc[5] + eps);
    double fg_pos = acc[1] / (acc[6] + eps);
    double pos = 0.5 * bg_pos + 0.5 * fg_pos;
    double neg = acc[2] / (acc[7] + eps);
    double dfg = acc[3] / (2.0 * acc[6] + eps);
    double dbg = acc[4] / (2.0 * acc[5] + eps);
    out[0] = (float)(0.5 * (pos + neg) + 0.5 * (dfg + dbg));
}

// ---------------- host ------------------------------------------------------
extern "C" void kernel_launch(void* const* d_in, const int* in_sizes, int n_in,
                              void* d_out, int out_size, void* d_ws, size_t ws_size,
                              hipStream_t stream) {
    const float* edge = (const float*)d_in[0];
    const float* dp   = (const float*)d_in[1];
    const float* bgl  = (const float*)d_in[2];
    const float* fgl  = (const float*)d_in[3];
    const float* ngl  = (const float*)d_in[4];
    const float* dt   = (const float*)d_in[5];
    const int* path_idx = (const int*)d_in[6];
    const int* src_idx  = (const int*)d_in[7];
    const int* dst_idx  = (const int*)d_in[8];

    int n_pos = in_sizes[7];
    int n_dst = in_sizes[8] / n_pos;
    int Lmax  = in_sizes[6] / (n_dst * n_pos);
    int B     = in_sizes[2] / (n_dst * n_pos);
    int HW    = in_sizes[0] / B;

    const int B_PER = 2;
    int BG = (B + B_PER - 1) / B_PER;
    int PB = (n_pos / 4 + 255) / 256;
    int nblk = n_dst * PB * BG;

    // workspace layout
    size_t part_bytes = (size_t)8 * nblk * sizeof(float);
    size_t need = part_bytes + 64 /*acc*/ + (size_t)n_dst * (Lmax + 1) * sizeof(int) + 64;
    bool use_atomic = (ws_size < need);

    float*  partials = (float*)d_ws;
    double* acc      = (double*)((char*)d_ws + (use_atomic ? 0 : part_bytes));
    int*    offs     = (int*)((char*)acc + 64);
    int*    doffs    = offs + (size_t)n_dst * Lmax;

    setup_kernel<<<1, 256, 0, stream>>>(path_idx, src_idx, dst_idx,
                                        n_dst, Lmax, n_pos, offs, doffs, acc);

    dim3 grid(n_dst * PB * BG);

#define LAUNCH(LM, AT) loss_kernel<LM, B_PER, AT><<<grid, 256, 0, stream>>>( \
        edge, dp, bgl, fgl, ngl, dt, src_idx, offs, doffs,                   \
        n_dst, n_pos, HW, B, PB, BG, Lmax, partials, nblk, acc)

    if (use_atomic) {
        if      (Lmax <= 8)  LAUNCH(8,  true);
        else if (Lmax <= 11) LAUNCH(11, true);
        else if (Lmax <= 16) LAUNCH(16, true);
        else if (Lmax <= 24) LAUNCH(24, true);
        else                 LAUNCH(32, true);
        finalize_atomic_kernel<<<1, 1, 0, stream>>>(acc, (float*)d_out);
    } else {
        if      (Lmax <= 8)  LAUNCH(8,  false);
        else if (Lmax <= 11) LAUNCH(11, false);
        else if (Lmax <= 16) LAUNCH(16, false);
        else if (Lmax <= 24) LAUNCH(24, false);
        else                 LAUNCH(32, false);
        reduce_kernel<<<1, 512, 0, stream>>>(partials, nblk, (float*)d_out);
    }
#undef LAUNCH
}